// Round 1
// baseline (96.502 us; speedup 1.0000x reference)
//
#include <hip/hip_runtime.h>

// LearnableDCT: x (32,3,512,512) f32, basis (64,64) f32
// out (32, 192, 64, 64) f32 : out[b][c*64+k][hb][wb] = sum_n basis[k][n] * block[n]
// block[n=i*8+j] = x[b][c][hb*8+i][wb*8+j]
//
// One thread per 8x8 block. lane == wb (blockDim multiple of 64) so
// x loads and out stores are coalesced along w.

__global__ __launch_bounds__(256) void dct_kernel(
    const float* __restrict__ x,
    const float* __restrict__ basis,
    float* __restrict__ out)
{
    const int tid    = blockIdx.x * 256 + threadIdx.x;
    const int within = tid & 4095;   // hb*64 + wb
    const int bc     = tid >> 12;    // (b*3 + c), 0..95
    const int wb     = within & 63;
    const int hb     = within >> 6;

    // x base for this block: bc*512*512 + (hb*8)*512 + wb*8
    const float* xp = x + ((size_t)bc << 18) + ((size_t)hb << 12) + (wb << 3);

    // load 8x8 block into registers (16x float4, all statically indexed)
    float xr[64];
    #pragma unroll
    for (int i = 0; i < 8; ++i) {
        float4 a = *reinterpret_cast<const float4*>(xp + i * 512);
        float4 c = *reinterpret_cast<const float4*>(xp + i * 512 + 4);
        xr[i * 8 + 0] = a.x; xr[i * 8 + 1] = a.y;
        xr[i * 8 + 2] = a.z; xr[i * 8 + 3] = a.w;
        xr[i * 8 + 4] = c.x; xr[i * 8 + 5] = c.y;
        xr[i * 8 + 6] = c.z; xr[i * 8 + 7] = c.w;
    }

    // out base: (bc*64 + k)*4096 + hb*64 + wb  =  bc*262144 + k*4096 + within
    float* op = out + ((size_t)bc << 18) + within;

    for (int k = 0; k < 64; ++k) {
        const float* bk = basis + (k << 6);  // wave-uniform -> scalar loads
        float a0 = 0.f, a1 = 0.f, a2 = 0.f, a3 = 0.f;
        #pragma unroll
        for (int n = 0; n < 64; n += 4) {
            a0 = fmaf(bk[n + 0], xr[n + 0], a0);
            a1 = fmaf(bk[n + 1], xr[n + 1], a1);
            a2 = fmaf(bk[n + 2], xr[n + 2], a2);
            a3 = fmaf(bk[n + 3], xr[n + 3], a3);
        }
        op[(size_t)k << 12] = (a0 + a1) + (a2 + a3);
    }
}

extern "C" void kernel_launch(void* const* d_in, const int* in_sizes, int n_in,
                              void* d_out, int out_size, void* d_ws, size_t ws_size,
                              hipStream_t stream) {
    const float* x     = (const float*)d_in[0];
    const float* basis = (const float*)d_in[1];
    float* out         = (float*)d_out;

    // total blocks = 32*3*64*64 = 393216 threads = 1536 workgroups of 256
    dct_kernel<<<dim3(1536), dim3(256), 0, stream>>>(x, basis, out);
}